// Round 10
// baseline (117.822 us; speedup 1.0000x reference)
//
#include <hip/hip_runtime.h>
#include <hip/hip_bf16.h>
#include <math.h>

#define C_    128
#define NQ_   8
#define NK_   32768
#define QNK_  (NQ_*NK_)
#define NCH_  256         // softmax chunks of 128 cols

// ws float offsets
#define AQ_OFF     0        // [q][o] 1024
#define MINKEY_OFF 1024     // 1 uint (order-preserving float key)
#define DENOM_OFF  1040     // 8*256
#define OUTV_OFF   4096     // 256*1024 -> 266240
#define WSA_OFF    266240   // A-frag table: 64 frags x 64 lanes x 8 bf16 = 16384 u32
#define BH_OFF     282624   // Bk frag table: 256 kt x 4 ct x 4 w x 64 lanes x 8 u32 = 2M u32

typedef float f32x4  __attribute__((ext_vector_type(4)));
typedef float f32x16 __attribute__((ext_vector_type(16)));
typedef int   i32x4  __attribute__((ext_vector_type(4)));
typedef short bf16x8 __attribute__((ext_vector_type(8)));
typedef unsigned int u32x4 __attribute__((ext_vector_type(4)));

__device__ inline unsigned short f2bf(float f){ // prep only
  unsigned u = __float_as_uint(f);
  return (unsigned short)((u + 0x7FFFu + ((u >> 16) & 1u)) >> 16);
}
__device__ inline unsigned int pkbf(float a, float b){
  __hip_bfloat162 h = __float22bfloat162_rn(make_float2(a, b)); // v_cvt_pk_bf16_f32
  union { __hip_bfloat162 h2; unsigned int u; } cv; cv.h2 = h; return cv.u;
}
__device__ inline float bf_lo(unsigned u){ return __uint_as_float(u << 16); }
__device__ inline float bf_hi(unsigned u){ return __uint_as_float(u & 0xFFFF0000u); }
__device__ inline unsigned int fkey(float f){
  unsigned u = __float_as_uint(f);
  return (u & 0x80000000u) ? ~u : (u | 0x80000000u);
}
__device__ inline float fkey_dec(unsigned key){
  unsigned u = (key & 0x80000000u) ? (key & 0x7FFFFFFFu) : ~key;
  return __uint_as_float(u);
}

// ---------------- prep0: A-frag table (32x32x16 layout) + Aq + minkey init ----
// frag f = part*32 + ot*8 + ks; element [f][l][e] =
//   W1[ (ot*32 + (l&31))*384 + 128 + part*128 + ks*16 + (l>>5)*8 + e ]
__global__ __launch_bounds__(256) void prep_kernel(const float* __restrict__ query,
    const float* __restrict__ W1, const float* __restrict__ b1, float* __restrict__ ws){
  const int t = threadIdx.x, b = blockIdx.x;
  if (b < 16){
    unsigned int* wsa = (unsigned int*)(ws + WSA_OFF);
    for (int u = b*1024 + t; u < (b+1)*1024; u += 256){
      unsigned int pack = 0;
#pragma unroll
      for (int e2 = 0; e2 < 2; e2++){
        const int E = u*2 + e2;
        const int f = E >> 9, l = (E >> 3) & 63, e = E & 7;
        const int part = f >> 5, ot = (f >> 3) & 3, ks = f & 7;
        const int o = ot*32 + (l & 31);
        const int c = ks*16 + ((l >> 5) << 3) + e;
        pack |= (unsigned int)f2bf(W1[o*384 + 128 + part*128 + c]) << (16*e2);
      }
      wsa[u] = pack;
    }
  } else {
    if (t == 0) *(unsigned int*)(ws + MINKEY_OFF) = 0xFFFFFFFFu;
    const int o = t >> 1, h = t & 1;
    float s[8];
#pragma unroll
    for (int q = 0; q < 8; q++) s[q] = 0.f;
    for (int c = h*64; c < h*64 + 64; c++){
      const float wv = W1[o*384 + c];
#pragma unroll
      for (int q = 0; q < 8; q++) s[q] += wv * query[c*8 + q];
    }
#pragma unroll
    for (int q = 0; q < 8; q++){
      s[q] += __shfl_xor(s[q], 1, 64);
      if (h == 0) ws[AQ_OFF + q*128 + o] = s[q] + b1[o];
    }
  }
}

// ---- staging layout (verified R8): fp32 [c][n]-global -> swizzled bf16 LDS ----
// element (n, c): byte = n*256 + ( (c*2 within row) ^ (((n>>2)&7)<<4) )
// thread slice: h = 2w + (l>>5) in 0..7 (c-octet pair), n4 = (l&31)*4.
__device__ inline void stage_load16(const float* __restrict__ dbase, size_t stride,
                                    f32x4* vv){
#pragma unroll
  for (int s = 0; s < 8; s++)
    vv[s]     = __builtin_nontemporal_load((const f32x4*)(dbase + (size_t)s*stride));
#pragma unroll
  for (int s = 0; s < 8; s++)
    vv[8 + s] = __builtin_nontemporal_load((const f32x4*)(dbase + (size_t)(64 + s)*stride));
}
__device__ inline void stage_write16(unsigned short* __restrict__ lds,
                                     int h, int n4, const f32x4* vv){
#pragma unroll
  for (int p = 0; p < 2; p++){
#pragma unroll
    for (int j = 0; j < 4; j++){
      const int n = n4 + j;
      u32x4 pk;
      pk[0] = pkbf(vv[p*8+0][j], vv[p*8+1][j]);
      pk[1] = pkbf(vv[p*8+2][j], vv[p*8+3][j]);
      pk[2] = pkbf(vv[p*8+4][j], vv[p*8+5][j]);
      pk[3] = pkbf(vv[p*8+6][j], vv[p*8+7][j]);
      const int byte = n*256 + ((h*16 + p*128) ^ (((n >> 2) & 7) << 4));
      *(u32x4*)((char*)lds + byte) = pk;
    }
  }
}
// combined (used by bkprep, identical layout)
__device__ inline void stage_tile(const float* __restrict__ src, size_t stride,
                                  unsigned short* __restrict__ lds, int w, int l){
  const int h  = 2*w + (l >> 5);
  const int n4 = (l & 31)*4;
  f32x4 vv[16];
  stage_load16(src + (size_t)(h*8)*stride + n4, stride, vv);
  stage_write16(lds, h, n4, vv);
}

// ---------------- bkprep: BH[kt][ct][w][lane][16] = C-frags of W1k x keys -----
__global__ __launch_bounds__(256) void bkprep_kernel(const float* __restrict__ keys,
    float* __restrict__ ws){
  __shared__ unsigned short b_lds[128*128]; // 128n x 128c bf16 = 32KB
  const int t = threadIdx.x, w = t >> 6, l = t & 63;
  const int blk = blockIdx.x, k0 = blk*128;

  const bf16x8* wsa8 = (const bf16x8*)(ws + WSA_OFF);
  bf16x8 afr[8];
#pragma unroll
  for (int ks = 0; ks < 8; ks++) afr[ks] = wsa8[(w*8 + ks)*64 + l];   // part 0

  stage_tile(keys + k0, NK_, b_lds, w, l);
  __syncthreads();

  unsigned int* bh = (unsigned int*)(ws + BH_OFF);
  const int nn = l & 31;
  const int cb2 = ((l >> 5) << 3)*2;   // byte offset of this lane's c-octet
#pragma unroll
  for (int ct = 0; ct < 4; ct++){
    f32x16 acc = {};
    const int n = ct*32 + nn;
    const int swz = ((n >> 2) & 7) << 4;
#pragma unroll
    for (int ks = 0; ks < 8; ks++){
      const int byte = n*256 + ((ks*32 + cb2) ^ swz);
      const bf16x8 bfr = *(const bf16x8*)((char*)b_lds + byte);
      acc = __builtin_amdgcn_mfma_f32_32x32x16_bf16(afr[ks], bfr, acc, 0, 0, 0);
    }
    u32x4 pA, pB;
#pragma unroll
    for (int j = 0; j < 4; j++){ pA[j] = pkbf(acc[2*j], acc[2*j+1]);
                                 pB[j] = pkbf(acc[8+2*j], acc[9+2*j]); }
    unsigned int* dst = bh + (size_t)(((blk*4 + ct)*4 + w)*64 + l)*8;
    *(u32x4*)dst = pA;
    *(u32x4*)(dst + 4) = pB;
  }
}

// ---------------- scores: 512 blocks = 256 strips x 2 q-halves, 4-q loop ------
// Per iter: issue next-tile loads early (T14), MFMA current, barrier, store,
// convert+write next tile, barrier. Constants amortized over 4 tiles.
__global__ __launch_bounds__(256, 3) void scores_kernel(
    const float* __restrict__ dist, const float* __restrict__ W2,
    const float* __restrict__ b2p, float* __restrict__ ws,
    float* __restrict__ scores)
{
  __shared__ unsigned short b_lds[128*128];   // 32KB swizzled [n][c]
  __shared__ float red[4][128];
  __shared__ float w2_lds[128];
  __shared__ float aq_lds[4*128];

  const int t = threadIdx.x, w = t >> 6, l = t & 63;
  const int kstrip = blockIdx.x & 255, qh = blockIdx.x >> 8;
  const int q0 = qh*4;
  const int k0 = kstrip*128;

  const int h  = 2*w + (l >> 5);
  const int n4 = (l & 31)*4;
  const float* dbase = dist + (size_t)q0*NK_ + k0 + (size_t)(h*8)*QNK_ + n4;

  // T14: issue first tile's loads before anything else
  f32x4 vv[16];
  stage_load16(dbase, QNK_, vv);

  // block constants (once per block, amortized over 4 q)
  const bf16x8* wsa8 = (const bf16x8*)(ws + WSA_OFF);
  bf16x8 afr[8];
#pragma unroll
  for (int ks = 0; ks < 8; ks++) afr[ks] = wsa8[(32 + w*8 + ks)*64 + l];  // part 1
  const unsigned int* bh = (const unsigned int*)(ws + BH_OFF);
  u32x4 bhA[4], bhB[4];
#pragma unroll
  for (int ct = 0; ct < 4; ct++){
    const unsigned int* src = bh + (size_t)(((kstrip*4 + ct)*4 + w)*64 + l)*8;
    bhA[ct] = *(const u32x4*)src;
    bhB[ct] = *(const u32x4*)(src + 4);
  }
  if (t < 128) w2_lds[t] = W2[t];
  for (int i = t; i < 512; i += 256) aq_lds[i] = ws[AQ_OFF + q0*128 + i];

  stage_write16(b_lds, h, n4, vv);     // waits vmcnt for tile q0
  __syncthreads();

  const int nn = l & 31;
  const int cb2 = ((l >> 5) << 3)*2;
  const int hi4 = (l >> 5) << 2;
  float minv = INFINITY;

#pragma unroll
  for (int qi = 0; qi < 4; qi++){
    if (qi < 3) stage_load16(dbase + (size_t)(qi+1)*NK_, QNK_, vv);  // issue early

    // MFMA on current tile + per-ct epilogue partials
#pragma unroll
    for (int ct = 0; ct < 4; ct++){
      f32x16 acc;
#pragma unroll
      for (int j = 0; j < 4; j++){
        acc[2*j]   = bf_lo(bhA[ct][j]);  acc[2*j+1] = bf_hi(bhA[ct][j]);
        acc[8+2*j] = bf_lo(bhB[ct][j]);  acc[9+2*j] = bf_hi(bhB[ct][j]);
      }
      const int n = ct*32 + nn;
      const int swz = ((n >> 2) & 7) << 4;
#pragma unroll
      for (int ks = 0; ks < 8; ks++){
        const int byte = n*256 + ((ks*32 + cb2) ^ swz);
        const bf16x8 bfr = *(const bf16x8*)((char*)b_lds + byte);
        acc = __builtin_amdgcn_mfma_f32_32x32x16_bf16(afr[ks], bfr, acc, 0, 0, 0);
      }
      float sl = 0.f;
#pragma unroll
      for (int r = 0; r < 16; r++){
        const int orow = w*32 + (r & 3) + 8*(r >> 2) + hi4;
        sl += w2_lds[orow] * fmaxf(acc[r] + aq_lds[qi*128 + orow], 0.f);
      }
      sl += __shfl_xor(sl, 32, 64);
      if (l < 32) red[w][ct*32 + l] = sl;
    }
    __syncthreads();                       // red ready; b_lds reads done

    if (t < 128){
      const float s = b2p[0] + red[0][t] + red[1][t] + red[2][t] + red[3][t];
      __builtin_nontemporal_store(s, &scores[(size_t)(q0+qi)*NK_ + k0 + t]);
      minv = fminf(minv, s);
    }
    if (qi < 3){
      stage_write16(b_lds, h, n4, vv);     // waits vmcnt for tile qi+1
      __syncthreads();                     // next tile ready; red free
    }
  }

  if (t < 128){
#pragma unroll
    for (int off = 32; off > 0; off >>= 1) minv = fminf(minv, __shfl_xor(minv, off, 64));
    if (l == 0) atomicMin((unsigned int*)(ws + MINKEY_OFF), fkey(minv));
  }
}

// ---------------- softmax + PV partials ----------------
__global__ __launch_bounds__(256) void softmax_pv_kernel(
    const float* __restrict__ value, const int* __restrict__ mask,
    float* __restrict__ scores, float* __restrict__ ws)
{
  __shared__ float v_lds[128*128];    // XOR-swizzled [d][k]
  __shared__ __align__(16) float e_lds[8][128];
  __shared__ float wsum[8];
  const int t = threadIdx.x, bid = blockIdx.x, k0 = bid*128;
  const float floorv = fkey_dec(*(const unsigned int*)(ws + MINKEY_OFF)) - 20.0f;

  for (int i = t; i < 4096; i += 256){
    const int d = i >> 5, k4 = (i & 31)*4;
    const f32x4 v = __builtin_nontemporal_load((const f32x4*)&value[(size_t)d*NK_ + k0 + k4]);
    const int dw = (d*128 + k4) ^ ((d & 31) << 2);
    *(f32x4*)&v_lds[dw] = v;
  }

  {
    const int q = t >> 5, kk = (t & 31)*4;
    const size_t gi = (size_t)q*NK_ + k0 + kk;
    const f32x4 s4 = *(const f32x4*)&scores[gi];
    const i32x4 m4 = *(const i32x4*)&mask[gi];
    f32x4 sf, e;
#pragma unroll
    for (int j = 0; j < 4; j++){
      sf[j] = m4[j] ? s4[j] : s4[j] + floorv;
      e[j]  = __expf(sf[j]);
    }
    __builtin_nontemporal_store(sf, (f32x4*)&scores[gi]);   // final masked scores
    *(f32x4*)&e_lds[q][kk] = e;
    float es = e[0] + e[1] + e[2] + e[3];
#pragma unroll
    for (int off = 16; off > 0; off >>= 1) es += __shfl_xor(es, off, 64);
    if ((t & 31) == 0) wsum[q] = es;
  }
  __syncthreads();
  if (t < 8) ws[DENOM_OFF + t*NCH_ + bid] = wsum[t];

  const int d = t & 127, qb = (t >> 7)*4;
  f32x4 acc = {0.f,0.f,0.f,0.f};
#pragma unroll 8
  for (int k4 = 0; k4 < 128; k4 += 4){
    const int dw = (d*128 + k4) ^ ((d & 31) << 2);
    const f32x4 v  = *(const f32x4*)&v_lds[dw];
    const f32x4 e0 = *(const f32x4*)&e_lds[qb+0][k4];
    const f32x4 e1 = *(const f32x4*)&e_lds[qb+1][k4];
    const f32x4 e2 = *(const f32x4*)&e_lds[qb+2][k4];
    const f32x4 e3 = *(const f32x4*)&e_lds[qb+3][k4];
#pragma unroll
    for (int j = 0; j < 4; j++){
      acc[0] += v[j]*e0[j]; acc[1] += v[j]*e1[j];
      acc[2] += v[j]*e2[j]; acc[3] += v[j]*e3[j];
    }
  }
#pragma unroll
  for (int j = 0; j < 4; j++) ws[OUTV_OFF + (size_t)bid*1024 + d*8 + qb + j] = acc[j];
}

// ---------------- finalize: 32 blocks, coalesced chunk reduce ----------------
__global__ __launch_bounds__(256) void finalize_kernel(const float* __restrict__ ws,
    float* __restrict__ out){
  __shared__ float dsum[8];
  __shared__ float red[8][32];
  const int t = threadIdx.x, bid = blockIdx.x;

  if (t < 64){
    const int q = t >> 3, i = t & 7;
    float s = 0.f;
    for (int j = 0; j < 32; j++) s += ws[DENOM_OFF + q*NCH_ + i + 8*j];
#pragma unroll
    for (int off = 4; off > 0; off >>= 1) s += __shfl_xor(s, off, 64);
    if (i == 0) dsum[q] = s;
  }

  const int ol = t & 31, part = t >> 5;
  float s = 0.f;
  for (int j = 0; j < 32; j++)
    s += ws[OUTV_OFF + (size_t)(part + 8*j)*1024 + bid*32 + ol];
  red[part][ol] = s;
  __syncthreads();

  if (t < 32){
    float a = 0.f;
#pragma unroll
    for (int p = 0; p < 8; p++) a += red[p][t];
    const int o = bid*32 + t;
    out[o] = a / dsum[o & 7];
  }
}

extern "C" void kernel_launch(void* const* d_in, const int* in_sizes, int n_in,
                              void* d_out, int out_size, void* d_ws, size_t ws_size,
                              hipStream_t stream){
  const float* query=(const float*)d_in[0];
  const float* keys =(const float*)d_in[1];
  const float* value=(const float*)d_in[2];
  const float* dist =(const float*)d_in[3];
  const int*   mask =(const int*)d_in[4];
  const float* W1   =(const float*)d_in[5];
  const float* b1   =(const float*)d_in[6];
  const float* W2   =(const float*)d_in[7];
  const float* b2   =(const float*)d_in[8];
  float* out=(float*)d_out;
  float* scores=out+1024;
  float* ws=(float*)d_ws;

  prep_kernel      <<<17,256,0,stream>>>(query,W1,b1,ws);
  bkprep_kernel    <<<256,256,0,stream>>>(keys,ws);
  scores_kernel    <<<512,256,0,stream>>>(dist,W2,b2,ws,scores);
  softmax_pv_kernel<<<NCH_,256,0,stream>>>(value,mask,scores,ws);
  finalize_kernel  <<<32,256,0,stream>>>(ws,out);
}

// Round 11
// 100.057 us; speedup vs baseline: 1.1775x; 1.1775x over previous
//
#include <hip/hip_runtime.h>
#include <hip/hip_bf16.h>
#include <math.h>

#define C_    128
#define NQ_   8
#define NK_   32768
#define QNK_  (NQ_*NK_)
#define NCH_  256         // softmax chunks of 128 cols

// ws float offsets
#define AQ_OFF     0        // [q][o] 1024
#define MINKEY_OFF 1024     // 1 uint (order-preserving float key)
#define DENOM_OFF  1040     // 8*256
#define OUTV_OFF   4096     // 256*1024 -> 266240
#define WSA_OFF    266240   // A-frag table: 64 frags x 64 lanes x 8 bf16 = 16384 u32
#define BH_OFF     282624   // Bk frag table: 256 kt x 4 ct x 4 w x 64 lanes x 8 u32 = 2M u32

typedef float f32x4  __attribute__((ext_vector_type(4)));
typedef float f32x16 __attribute__((ext_vector_type(16)));
typedef int   i32x4  __attribute__((ext_vector_type(4)));
typedef short bf16x8 __attribute__((ext_vector_type(8)));
typedef unsigned int u32x4 __attribute__((ext_vector_type(4)));

__device__ inline unsigned short f2bf(float f){ // prep only
  unsigned u = __float_as_uint(f);
  return (unsigned short)((u + 0x7FFFu + ((u >> 16) & 1u)) >> 16);
}
__device__ inline unsigned int pkbf(float a, float b){
  __hip_bfloat162 h = __float22bfloat162_rn(make_float2(a, b)); // v_cvt_pk_bf16_f32
  union { __hip_bfloat162 h2; unsigned int u; } cv; cv.h2 = h; return cv.u;
}
__device__ inline float bf_lo(unsigned u){ return __uint_as_float(u << 16); }
__device__ inline float bf_hi(unsigned u){ return __uint_as_float(u & 0xFFFF0000u); }
__device__ inline unsigned int fkey(float f){
  unsigned u = __float_as_uint(f);
  return (u & 0x80000000u) ? ~u : (u | 0x80000000u);
}
__device__ inline float fkey_dec(unsigned key){
  unsigned u = (key & 0x80000000u) ? (key & 0x7FFFFFFFu) : ~key;
  return __uint_as_float(u);
}

// ---------------- prep0: A-frag table (32x32x16 layout) + Aq + minkey init ----
// frag f = part*32 + ot*8 + ks; element [f][l][e] =
//   W1[ (ot*32 + (l&31))*384 + 128 + part*128 + ks*16 + (l>>5)*8 + e ]
__global__ __launch_bounds__(256) void prep_kernel(const float* __restrict__ query,
    const float* __restrict__ W1, const float* __restrict__ b1, float* __restrict__ ws){
  const int t = threadIdx.x, b = blockIdx.x;
  if (b < 16){
    unsigned int* wsa = (unsigned int*)(ws + WSA_OFF);
    for (int u = b*1024 + t; u < (b+1)*1024; u += 256){
      unsigned int pack = 0;
#pragma unroll
      for (int e2 = 0; e2 < 2; e2++){
        const int E = u*2 + e2;
        const int f = E >> 9, l = (E >> 3) & 63, e = E & 7;
        const int part = f >> 5, ot = (f >> 3) & 3, ks = f & 7;
        const int o = ot*32 + (l & 31);
        const int c = ks*16 + ((l >> 5) << 3) + e;
        pack |= (unsigned int)f2bf(W1[o*384 + 128 + part*128 + c]) << (16*e2);
      }
      wsa[u] = pack;
    }
  } else {
    if (t == 0) *(unsigned int*)(ws + MINKEY_OFF) = 0xFFFFFFFFu;
    const int o = t >> 1, h = t & 1;
    float s[8];
#pragma unroll
    for (int q = 0; q < 8; q++) s[q] = 0.f;
    for (int c = h*64; c < h*64 + 64; c++){
      const float wv = W1[o*384 + c];
#pragma unroll
      for (int q = 0; q < 8; q++) s[q] += wv * query[c*8 + q];
    }
#pragma unroll
    for (int q = 0; q < 8; q++){
      s[q] += __shfl_xor(s[q], 1, 64);
      if (h == 0) ws[AQ_OFF + q*128 + o] = s[q] + b1[o];
    }
  }
}

// ---- staging layout (verified R8): fp32 [c][n]-global -> swizzled bf16 LDS ----
// element (n, c): byte = n*256 + ( (c*2 within row) ^ (((n>>2)&7)<<4) )
// thread slice: h = 2w + (l>>5) in 0..7 (c-octet pair), n4 = (l&31)*4.
__device__ inline void stage_load16(const float* __restrict__ dbase, size_t stride,
                                    f32x4* vv){
#pragma unroll
  for (int s = 0; s < 8; s++)
    vv[s]     = __builtin_nontemporal_load((const f32x4*)(dbase + (size_t)s*stride));
#pragma unroll
  for (int s = 0; s < 8; s++)
    vv[8 + s] = __builtin_nontemporal_load((const f32x4*)(dbase + (size_t)(64 + s)*stride));
}
__device__ inline void stage_write16(unsigned short* __restrict__ lds,
                                     int h, int n4, const f32x4* vv){
#pragma unroll
  for (int p = 0; p < 2; p++){
#pragma unroll
    for (int j = 0; j < 4; j++){
      const int n = n4 + j;
      u32x4 pk;
      pk[0] = pkbf(vv[p*8+0][j], vv[p*8+1][j]);
      pk[1] = pkbf(vv[p*8+2][j], vv[p*8+3][j]);
      pk[2] = pkbf(vv[p*8+4][j], vv[p*8+5][j]);
      pk[3] = pkbf(vv[p*8+6][j], vv[p*8+7][j]);
      const int byte = n*256 + ((h*16 + p*128) ^ (((n >> 2) & 7) << 4));
      *(u32x4*)((char*)lds + byte) = pk;
    }
  }
}
// combined (used by bkprep, identical layout)
__device__ inline void stage_tile(const float* __restrict__ src, size_t stride,
                                  unsigned short* __restrict__ lds, int w, int l){
  const int h  = 2*w + (l >> 5);
  const int n4 = (l & 31)*4;
  f32x4 vv[16];
  stage_load16(src + (size_t)(h*8)*stride + n4, stride, vv);
  stage_write16(lds, h, n4, vv);
}

// ---------------- bkprep: BH[kt][ct][w][lane][16] = C-frags of W1k x keys -----
__global__ __launch_bounds__(256) void bkprep_kernel(const float* __restrict__ keys,
    float* __restrict__ ws){
  __shared__ unsigned short b_lds[128*128]; // 128n x 128c bf16 = 32KB
  const int t = threadIdx.x, w = t >> 6, l = t & 63;
  const int blk = blockIdx.x, k0 = blk*128;

  const bf16x8* wsa8 = (const bf16x8*)(ws + WSA_OFF);
  bf16x8 afr[8];
#pragma unroll
  for (int ks = 0; ks < 8; ks++) afr[ks] = wsa8[(w*8 + ks)*64 + l];   // part 0

  stage_tile(keys + k0, NK_, b_lds, w, l);
  __syncthreads();

  unsigned int* bh = (unsigned int*)(ws + BH_OFF);
  const int nn = l & 31;
  const int cb2 = ((l >> 5) << 3)*2;   // byte offset of this lane's c-octet
#pragma unroll
  for (int ct = 0; ct < 4; ct++){
    f32x16 acc = {};
    const int n = ct*32 + nn;
    const int swz = ((n >> 2) & 7) << 4;
#pragma unroll
    for (int ks = 0; ks < 8; ks++){
      const int byte = n*256 + ((ks*32 + cb2) ^ swz);
      const bf16x8 bfr = *(const bf16x8*)((char*)b_lds + byte);
      acc = __builtin_amdgcn_mfma_f32_32x32x16_bf16(afr[ks], bfr, acc, 0, 0, 0);
    }
    u32x4 pA, pB;
#pragma unroll
    for (int j = 0; j < 4; j++){ pA[j] = pkbf(acc[2*j], acc[2*j+1]);
                                 pB[j] = pkbf(acc[8+2*j], acc[9+2*j]); }
    unsigned int* dst = bh + (size_t)(((blk*4 + ct)*4 + w)*64 + l)*8;
    *(u32x4*)dst = pA;
    *(u32x4*)(dst + 4) = pB;
  }
}

// ---------------- scores: 1024 blocks = 256 strips x 4 q-pairs, 2-q loop ------
// T14 pinned: prefetch loads issued BEFORE the MFMA phase and held live across
// it via sched_barrier(0) (R10 showed the scheduler otherwise sinks them).
__global__ __launch_bounds__(256, 3) void scores_kernel(
    const float* __restrict__ dist, const float* __restrict__ W2,
    const float* __restrict__ b2p, float* __restrict__ ws,
    float* __restrict__ scores)
{
  __shared__ unsigned short b_lds[128*128];   // 32KB swizzled [n][c]
  __shared__ float red[4][128];
  __shared__ float w2_lds[128];
  __shared__ float aq_lds[2*128];

  const int t = threadIdx.x, w = t >> 6, l = t & 63;
  const int kstrip = blockIdx.x & 255, qp = blockIdx.x >> 8;   // qp in 0..3
  const int q0 = qp*2;
  const int k0 = kstrip*128;

  const int h  = 2*w + (l >> 5);
  const int n4 = (l & 31)*4;
  const float* dbase = dist + (size_t)q0*NK_ + k0 + (size_t)(h*8)*QNK_ + n4;

  // issue first tile's loads before anything else
  f32x4 vv[16];
  stage_load16(dbase, QNK_, vv);

  // block constants (once per block, amortized over 2 q)
  const bf16x8* wsa8 = (const bf16x8*)(ws + WSA_OFF);
  bf16x8 afr[8];
#pragma unroll
  for (int ks = 0; ks < 8; ks++) afr[ks] = wsa8[(32 + w*8 + ks)*64 + l];  // part 1
  const unsigned int* bh = (const unsigned int*)(ws + BH_OFF);
  u32x4 bhA[4], bhB[4];
#pragma unroll
  for (int ct = 0; ct < 4; ct++){
    const unsigned int* src = bh + (size_t)(((kstrip*4 + ct)*4 + w)*64 + l)*8;
    bhA[ct] = *(const u32x4*)src;
    bhB[ct] = *(const u32x4*)(src + 4);
  }
  if (t < 128) w2_lds[t] = W2[t];
  for (int i = t; i < 256; i += 256) aq_lds[i] = ws[AQ_OFF + q0*128 + i];
  if (t + 256 < 512) ; // (aq is 256 floats: loop above covers t<256)
  aq_lds[t & 255] = ws[AQ_OFF + q0*128 + (t & 255)];

  stage_write16(b_lds, h, n4, vv);     // waits vmcnt for tile q0
  __syncthreads();

  const int nn = l & 31;
  const int cb2 = ((l >> 5) << 3)*2;
  const int hi4 = (l >> 5) << 2;
  float minv = INFINITY;

#pragma unroll
  for (int qi = 0; qi < 2; qi++){
    if (qi < 1){
      stage_load16(dbase + NK_, QNK_, vv);          // issue tile q0+1 early
      __builtin_amdgcn_sched_barrier(0);            // PIN: loads stay above MFMA
    }

    // MFMA on current tile + per-ct epilogue partials
#pragma unroll
    for (int ct = 0; ct < 4; ct++){
      f32x16 acc;
#pragma unroll
      for (int j = 0; j < 4; j++){
        acc[2*j]   = bf_lo(bhA[ct][j]);  acc[2*j+1] = bf_hi(bhA[ct][j]);
        acc[8+2*j] = bf_lo(bhB[ct][j]);  acc[9+2*j] = bf_hi(bhB[ct][j]);
      }
      const int n = ct*32 + nn;
      const int swz = ((n >> 2) & 7) << 4;
#pragma unroll
      for (int ks = 0; ks < 8; ks++){
        const int byte = n*256 + ((ks*32 + cb2) ^ swz);
        const bf16x8 bfr = *(const bf16x8*)((char*)b_lds + byte);
        acc = __builtin_amdgcn_mfma_f32_32x32x16_bf16(afr[ks], bfr, acc, 0, 0, 0);
      }
      float sl = 0.f;
#pragma unroll
      for (int r = 0; r < 16; r++){
        const int orow = w*32 + (r & 3) + 8*(r >> 2) + hi4;
        sl += w2_lds[orow] * fmaxf(acc[r] + aq_lds[qi*128 + orow], 0.f);
      }
      sl += __shfl_xor(sl, 32, 64);
      if (l < 32) red[w][ct*32 + l] = sl;
    }
    __syncthreads();                       // red ready; b_lds reads done

    if (t < 128){
      const float s = b2p[0] + red[0][t] + red[1][t] + red[2][t] + red[3][t];
      __builtin_nontemporal_store(s, &scores[(size_t)(q0+qi)*NK_ + k0 + t]);
      minv = fminf(minv, s);
    }
    if (qi < 1){
      stage_write16(b_lds, h, n4, vv);     // vmcnt waits here (one MFMA phase later)
      __syncthreads();                     // next tile ready; red free
    }
  }

  if (t < 128){
#pragma unroll
    for (int off = 32; off > 0; off >>= 1) minv = fminf(minv, __shfl_xor(minv, off, 64));
    if (l == 0) atomicMin((unsigned int*)(ws + MINKEY_OFF), fkey(minv));
  }
}

// ---------------- softmax + PV partials ----------------
__global__ __launch_bounds__(256) void softmax_pv_kernel(
    const float* __restrict__ value, const int* __restrict__ mask,
    float* __restrict__ scores, float* __restrict__ ws)
{
  __shared__ float v_lds[128*128];    // XOR-swizzled [d][k]
  __shared__ __align__(16) float e_lds[8][128];
  __shared__ float wsum[8];
  const int t = threadIdx.x, bid = blockIdx.x, k0 = bid*128;
  const float floorv = fkey_dec(*(const unsigned int*)(ws + MINKEY_OFF)) - 20.0f;

  for (int i = t; i < 4096; i += 256){
    const int d = i >> 5, k4 = (i & 31)*4;
    const f32x4 v = __builtin_nontemporal_load((const f32x4*)&value[(size_t)d*NK_ + k0 + k4]);
    const int dw = (d*128 + k4) ^ ((d & 31) << 2);
    *(f32x4*)&v_lds[dw] = v;
  }

  {
    const int q = t >> 5, kk = (t & 31)*4;
    const size_t gi = (size_t)q*NK_ + k0 + kk;
    const f32x4 s4 = *(const f32x4*)&scores[gi];
    const i32x4 m4 = *(const i32x4*)&mask[gi];
    f32x4 sf, e;
#pragma unroll
    for (int j = 0; j < 4; j++){
      sf[j] = m4[j] ? s4[j] : s4[j] + floorv;
      e[j]  = __expf(sf[j]);
    }
    __builtin_nontemporal_store(sf, (f32x4*)&scores[gi]);   // final masked scores
    *(f32x4*)&e_lds[q][kk] = e;
    float es = e[0] + e[1] + e[2] + e[3];
#pragma unroll
    for (int off = 16; off > 0; off >>= 1) es += __shfl_xor(es, off, 64);
    if ((t & 31) == 0) wsum[q] = es;
  }
  __syncthreads();
  if (t < 8) ws[DENOM_OFF + t*NCH_ + bid] = wsum[t];

  const int d = t & 127, qb = (t >> 7)*4;
  f32x4 acc = {0.f,0.f,0.f,0.f};
#pragma unroll 8
  for (int k4 = 0; k4 < 128; k4 += 4){
    const int dw = (d*128 + k4) ^ ((d & 31) << 2);
    const f32x4 v  = *(const f32x4*)&v_lds[dw];
    const f32x4 e0 = *(const f32x4*)&e_lds[qb+0][k4];
    const f32x4 e1 = *(const f32x4*)&e_lds[qb+1][k4];
    const f32x4 e2 = *(const f32x4*)&e_lds[qb+2][k4];
    const f32x4 e3 = *(const f32x4*)&e_lds[qb+3][k4];
#pragma unroll
    for (int j = 0; j < 4; j++){
      acc[0] += v[j]*e0[j]; acc[1] += v[j]*e1[j];
      acc[2] += v[j]*e2[j]; acc[3] += v[j]*e3[j];
    }
  }
#pragma unroll
  for (int j = 0; j < 4; j++) ws[OUTV_OFF + (size_t)bid*1024 + d*8 + qb + j] = acc[j];
}

// ---------------- finalize: 32 blocks, coalesced chunk reduce ----------------
__global__ __launch_bounds__(256) void finalize_kernel(const float* __restrict__ ws,
    float* __restrict__ out){
  __shared__ float dsum[8];
  __shared__ float red[8][32];
  const int t = threadIdx.x, bid = blockIdx.x;

  if (t < 64){
    const int q = t >> 3, i = t & 7;
    float s = 0.f;
    for (int j = 0; j < 32; j++) s += ws[DENOM_OFF + q*NCH_ + i + 8*j];
#pragma unroll
    for (int off = 4; off > 0; off >>= 1) s += __shfl_xor(s, off, 64);
    if (i == 0) dsum[q] = s;
  }

  const int ol = t & 31, part = t >> 5;
  float s = 0.f;
  for (int j = 0; j < 32; j++)
    s += ws[OUTV_OFF + (size_t)(part + 8*j)*1024 + bid*32 + ol];
  red[part][ol] = s;
  __syncthreads();

  if (t < 32){
    float a = 0.f;
#pragma unroll
    for (int p = 0; p < 8; p++) a += red[p][t];
    const int o = bid*32 + t;
    out[o] = a / dsum[o & 7];
  }
}

extern "C" void kernel_launch(void* const* d_in, const int* in_sizes, int n_in,
                              void* d_out, int out_size, void* d_ws, size_t ws_size,
                              hipStream_t stream){
  const float* query=(const float*)d_in[0];
  const float* keys =(const float*)d_in[1];
  const float* value=(const float*)d_in[2];
  const float* dist =(const float*)d_in[3];
  const int*   mask =(const int*)d_in[4];
  const float* W1   =(const float*)d_in[5];
  const float* b1   =(const float*)d_in[6];
  const float* W2   =(const float*)d_in[7];
  const float* b2   =(const float*)d_in[8];
  float* out=(float*)d_out;
  float* scores=out+1024;
  float* ws=(float*)d_ws;

  prep_kernel      <<<17,256,0,stream>>>(query,W1,b1,ws);
  bkprep_kernel    <<<256,256,0,stream>>>(keys,ws);
  scores_kernel    <<<1024,256,0,stream>>>(dist,W2,b2,ws,scores);
  softmax_pv_kernel<<<NCH_,256,0,stream>>>(value,mask,scores,ws);
  finalize_kernel  <<<32,256,0,stream>>>(ws,out);
}

// Round 12
// 80.645 us; speedup vs baseline: 1.4610x; 1.2407x over previous
//
#include <hip/hip_runtime.h>
#include <hip/hip_bf16.h>
#include <math.h>

#define C_    128
#define NQ_   8
#define NK_   32768
#define QNK_  (NQ_*NK_)
#define NCH_  256         // softmax chunks of 128 cols

// ws float offsets
#define AQ_OFF     0        // [q][o] 1024
#define MINKEY_OFF 1024     // 1 uint (order-preserving float key)
#define DENOM_OFF  1040     // 8*256
#define OUTV_OFF   4096     // 256*1024
#define WSA_OFF    266240   // bf16 A-frag table: 64 frags x 64 lanes x 8 bf16

typedef float f32x4 __attribute__((ext_vector_type(4)));
typedef int   i32x4 __attribute__((ext_vector_type(4)));
typedef short bf16x8 __attribute__((ext_vector_type(8)));

__device__ inline unsigned short f2bf(float f){ // prep only
  unsigned u = __float_as_uint(f);
  return (unsigned short)((u + 0x7FFFu + ((u >> 16) & 1u)) >> 16);
}
__device__ inline unsigned int pkbf(float a, float b){
  __hip_bfloat162 h = __float22bfloat162_rn(make_float2(a, b)); // v_cvt_pk_bf16_f32
  union { __hip_bfloat162 h2; unsigned int u; } cv; cv.h2 = h; return cv.u;
}
__device__ inline unsigned int fkey(float f){   // monotone float->uint
  unsigned u = __float_as_uint(f);
  return (u & 0x80000000u) ? ~u : (u | 0x80000000u);
}
__device__ inline float fkey_dec(unsigned key){
  unsigned u = (key & 0x80000000u) ? (key & 0x7FFFFFFFu) : ~key;
  return __uint_as_float(u);
}
__device__ inline int swz8(int r){ return ((r ^ (r >> 3)) & 7) << 3; }

// ---------------- prep: 17 blocks. 0..15: A-frag table. 16: Aq + atomic init.
// (byte-identical to round 5 — verified)
__global__ __launch_bounds__(256) void prep_kernel(const float* __restrict__ query,
    const float* __restrict__ W1, const float* __restrict__ b1, float* __restrict__ ws){
  const int t = threadIdx.x, b = blockIdx.x;
  if (b < 16){
    unsigned int* wsa = (unsigned int*)(ws + WSA_OFF);
    for (int u = b*1024 + t; u < (b+1)*1024; u += 256){
      unsigned int pack = 0;
#pragma unroll
      for (int e2 = 0; e2 < 2; e2++){
        const int E = u*2 + e2;
        const int f = E >> 9, lane = (E >> 3) & 63, e = E & 7;
        const int w = f >> 4, r = f & 15;
        const int part = r >> 3, ks = (r >> 1) & 3, of = r & 1;
        const int o = w*32 + of*16 + (lane & 15);
        const int c = ks*32 + ((lane >> 4) << 3) + e;
        pack |= (unsigned int)f2bf(W1[o*384 + 128 + part*128 + c]) << (16*e2);
      }
      wsa[u] = pack;
    }
  } else {
    if (t == 0) *(unsigned int*)(ws + MINKEY_OFF) = 0xFFFFFFFFu;
    const int o = t >> 1, h = t & 1;   // 2 threads per o
    float s[8];
#pragma unroll
    for (int q = 0; q < 8; q++) s[q] = 0.f;
    for (int c = h*64; c < h*64 + 64; c++){
      const float wv = W1[o*384 + c];
#pragma unroll
      for (int q = 0; q < 8; q++) s[q] += wv * query[c*8 + q];
    }
#pragma unroll
    for (int q = 0; q < 8; q++){
      s[q] += __shfl_xor(s[q], 1, 64);
      if (h == 0) ws[AQ_OFF + q*128 + o] = s[q] + b1[o];
    }
  }
}

// ---- half-tile staging (R5 layout, 4xf32x4 regs): rows p0*32..(p0+1)*32+c2+1 ----
template<bool NT>
__device__ inline void stage8_load(const float* __restrict__ base, size_t rstride,
                                   int p0, f32x4* vv){
#pragma unroll
  for (int pp = 0; pp < 2; pp++){
    const float* pa = base + (size_t)((p0 + pp)*32)*rstride;
    if (NT){ vv[pp*2+0] = __builtin_nontemporal_load((const f32x4*)pa);
             vv[pp*2+1] = __builtin_nontemporal_load((const f32x4*)(pa + rstride)); }
    else   { vv[pp*2+0] = *(const f32x4*)pa; vv[pp*2+1] = *(const f32x4*)(pa + rstride); }
  }
}
__device__ inline void stage8_write(unsigned short* __restrict__ lds,
                                    int skl4, int c2, int p0, const f32x4* vv){
#pragma unroll
  for (int pp = 0; pp < 2; pp++){
    const int c = (p0 + pp)*32 + c2;
#pragma unroll
    for (int j = 0; j < 4; j++){
      const int kl = skl4 + j;
      const int idx = (kl*128 + c) ^ swz8(kl);
      *(unsigned int*)&lds[idx] = pkbf(vv[pp*2+0][j], vv[pp*2+1][j]);
    }
  }
}
__device__ inline bf16x8 frag16_read(const unsigned short* __restrict__ lds,
                                     int ks, int g, int li){
  const int idx = (li << 7) + (((ks << 5) + (g << 3)) ^ swz8(li));
  return *(const bf16x8*)&lds[idx];
}

// ---------------- scores: R5 skeleton, 12 waves/CU, half-tile pipeline --------
__global__ __launch_bounds__(256, 3) void scores_kernel(
    const float* __restrict__ keys, const float* __restrict__ dist,
    const float* __restrict__ W2, const float* __restrict__ b2p,
    float* __restrict__ ws, float* __restrict__ scores)
{
  __shared__ unsigned short a_lds[32*512];     // 32 KB frag slots
  __shared__ unsigned short d_lds[4][16*128];  // 4 x 4 KB wave-private
  __shared__ float aq_lds[4*128];              // this block's 4 q rows
  __shared__ float w2_lds[128];
  __shared__ float minred[4];

  const int t = threadIdx.x, w = t >> 6, l = t & 63;
  const int g = l >> 4, li = l & 15;
  const int kb = blockIdx.x >> 1, qh = blockIdx.x & 1;
  const int q0 = qh*4;
  const int k0w = kb*64 + w*16;
  unsigned short* dw = d_lds[w];
  const int skl4 = (l & 3)*4, c2 = (l >> 2)*2;

  const float* kbase = keys + (size_t)c2*NK_  + k0w + skl4;
  const float* dbase = dist + (size_t)q0*NK_ + (size_t)c2*QNK_ + k0w + skl4;

  // cooperative: W1-keys frag slots + aq + w2
  const unsigned int* wsaU = (const unsigned int*)(ws + WSA_OFF);
  unsigned int* aU = (unsigned int*)a_lds;
  for (int i = t; i < 8192; i += 256){
    const int s = i >> 8, r = i & 255;
    aU[i] = wsaU[((s >> 3)*16 + (s & 7))*256 + r];
  }
  for (int i = t; i < 512; i += 256) aq_lds[i] = ws[AQ_OFF + q0*128 + i];
  if (t < 128) w2_lds[t] = W2[t];

  // wave-private: stage keys (two halves), then issue dist q0 H1
  f32x4 vv[4];
  stage8_load<false>(kbase, NK_, 0, vv);
  stage8_write(dw, skl4, c2, 0, vv);
  stage8_load<false>(kbase, NK_, 2, vv);
  stage8_write(dw, skl4, c2, 2, vv);
  stage8_load<true>(dbase, QNK_, 0, vv);       // L_h1(q0) in flight across bk
  __builtin_amdgcn_sched_barrier(0);
  __syncthreads();                             // a_lds(W1k), aq, w2 ready

  // Bk accumulators (keys part), reused for the 4 q's
  f32x4 bk[8];
#pragma unroll
  for (int f = 0; f < 8; f++){ f32x4 z = {0.f,0.f,0.f,0.f}; bk[f] = z; }
#pragma unroll
  for (int ks = 0; ks < 4; ks++){
    const bf16x8 bfr = frag16_read(dw, ks, g, li);
#pragma unroll
    for (int of8 = 0; of8 < 8; of8++){
      const int s = (of8 >> 1)*8 + ks*2 + (of8 & 1);
      const bf16x8 a = *(const bf16x8*)&a_lds[s*512 + l*8];
      bk[of8] = __builtin_amdgcn_mfma_f32_16x16x32_bf16(a, bfr, bk[of8], 0,0,0);
    }
  }
  __syncthreads();                             // all waves done with W1k slots

  // cooperative: overwrite slots with W1-dist frags
  for (int i = t; i < 8192; i += 256){
    const int s = i >> 8, r = i & 255;
    aU[i] = wsaU[((s >> 3)*16 + 8 + (s & 7))*256 + r];
  }
  // wave-private: write H1(q0) (waits its loads), issue H2(q0)
  stage8_write(dw, skl4, c2, 0, vv);
  stage8_load<true>(dbase, QNK_, 2, vv);
  __builtin_amdgcn_sched_barrier(0);
  __syncthreads();                             // a_lds(W1d) ready

  const float b2v = b2p[0];
  float minv = INFINITY;

#pragma unroll
  for (int qi = 0; qi < 4; qi++){
    f32x4 acc[8];
#pragma unroll
    for (int f = 0; f < 8; f++) acc[f] = bk[f];

    // ks 0,1 on H1 (c 0..63)
#pragma unroll
    for (int ks = 0; ks < 2; ks++){
      const bf16x8 bfr = frag16_read(dw, ks, g, li);
#pragma unroll
      for (int of8 = 0; of8 < 8; of8++){
        const int s = (of8 >> 1)*8 + ks*2 + (of8 & 1);
        const bf16x8 a = *(const bf16x8*)&a_lds[s*512 + l*8];
        acc[of8] = __builtin_amdgcn_mfma_f32_16x16x32_bf16(a, bfr, acc[of8], 0,0,0);
      }
    }

    stage8_write(dw, skl4, c2, 2, vv);         // H2(qi): waits L_h2(qi)
    if (qi < 3){
      stage8_load<true>(dbase + (size_t)(qi+1)*NK_, QNK_, 0, vv);  // L_h1(qi+1)
      __builtin_amdgcn_sched_barrier(0);
    }

    // ks 2,3 on H2 (c 64..127)
#pragma unroll
    for (int ks = 2; ks < 4; ks++){
      const bf16x8 bfr = frag16_read(dw, ks, g, li);
#pragma unroll
      for (int of8 = 0; of8 < 8; of8++){
        const int s = (of8 >> 1)*8 + ks*2 + (of8 & 1);
        const bf16x8 a = *(const bf16x8*)&a_lds[s*512 + l*8];
        acc[of8] = __builtin_amdgcn_mfma_f32_16x16x32_bf16(a, bfr, acc[of8], 0,0,0);
      }
    }

    // epilogue
    float sv = 0.f;
#pragma unroll
    for (int of8 = 0; of8 < 8; of8++){
      const int ob = (of8 >> 1)*32 + (of8 & 1)*16 + g*4;
      const f32x4 aqv = *(const f32x4*)&aq_lds[qi*128 + ob];
      const f32x4 w2v = *(const f32x4*)&w2_lds[ob];
#pragma unroll
      for (int r = 0; r < 4; r++)
        sv += w2v[r] * fmaxf(acc[of8][r] + aqv[r], 0.f);
    }
    sv += __shfl_xor(sv, 16, 64);
    sv += __shfl_xor(sv, 32, 64);
    sv += b2v;
    if (l < 16)
      __builtin_nontemporal_store(sv, &scores[(size_t)(q0+qi)*NK_ + k0w + l]);
    minv = fminf(minv, sv);

    if (qi < 3){
      stage8_write(dw, skl4, c2, 0, vv);       // H1(qi+1): waits L_h1(qi+1)
      stage8_load<true>(dbase + (size_t)(qi+1)*NK_, QNK_, 2, vv);  // L_h2(qi+1)
      __builtin_amdgcn_sched_barrier(0);
    }
  }

#pragma unroll
  for (int off = 32; off > 0; off >>= 1) minv = fminf(minv, __shfl_xor(minv, off, 64));
  if (l == 0) minred[w] = minv;
  __syncthreads();
  if (t == 0){
    const float m = fminf(fminf(minred[0], minred[1]), fminf(minred[2], minred[3]));
    atomicMin((unsigned int*)(ws + MINKEY_OFF), fkey(m));
  }
}

// ---------------- softmax + PV partials (R5, verified) ----------------
__global__ __launch_bounds__(256) void softmax_pv_kernel(
    const float* __restrict__ value, const int* __restrict__ mask,
    float* __restrict__ scores, float* __restrict__ ws)
{
  __shared__ float v_lds[128*128];    // XOR-swizzled [d][k]
  __shared__ __align__(16) float e_lds[8][128];
  __shared__ float wsum[8];
  const int t = threadIdx.x, bid = blockIdx.x, k0 = bid*128;
  const float floorv = fkey_dec(*(const unsigned int*)(ws + MINKEY_OFF)) - 20.0f;

  for (int i = t; i < 4096; i += 256){
    const int d = i >> 5, k4 = (i & 31)*4;
    const f32x4 v = __builtin_nontemporal_load((const f32x4*)&value[(size_t)d*NK_ + k0 + k4]);
    const int dw = (d*128 + k4) ^ ((d & 31) << 2);
    *(f32x4*)&v_lds[dw] = v;
  }

  {
    const int q = t >> 5, kk = (t & 31)*4;
    const size_t gi = (size_t)q*NK_ + k0 + kk;
    const f32x4 s4 = *(const f32x4*)&scores[gi];
    const i32x4 m4 = *(const i32x4*)&mask[gi];
    f32x4 sf, e;
#pragma unroll
    for (int j = 0; j < 4; j++){
      sf[j] = m4[j] ? s4[j] : s4[j] + floorv;
      e[j]  = __expf(sf[j]);
    }
    __builtin_nontemporal_store(sf, (f32x4*)&scores[gi]);   // final masked scores
    *(f32x4*)&e_lds[q][kk] = e;
    float es = e[0] + e[1] + e[2] + e[3];
#pragma unroll
    for (int off = 16; off > 0; off >>= 1) es += __shfl_xor(es, off, 64);
    if ((t & 31) == 0) wsum[q] = es;
  }
  __syncthreads();
  if (t < 8) ws[DENOM_OFF + t*NCH_ + bid] = wsum[t];

  const int d = t & 127, qb = (t >> 7)*4;
  f32x4 acc = {0.f,0.f,0.f,0.f};
#pragma unroll 8
  for (int k4 = 0; k4 < 128; k4 += 4){
    const int dw = (d*128 + k4) ^ ((d & 31) << 2);
    const f32x4 v  = *(const f32x4*)&v_lds[dw];
    const f32x4 e0 = *(const f32x4*)&e_lds[qb+0][k4];
    const f32x4 e1 = *(const f32x4*)&e_lds[qb+1][k4];
    const f32x4 e2 = *(const f32x4*)&e_lds[qb+2][k4];
    const f32x4 e3 = *(const f32x4*)&e_lds[qb+3][k4];
#pragma unroll
    for (int j = 0; j < 4; j++){
      acc[0] += v[j]*e0[j]; acc[1] += v[j]*e1[j];
      acc[2] += v[j]*e2[j]; acc[3] += v[j]*e3[j];
    }
  }
#pragma unroll
  for (int j = 0; j < 4; j++) ws[OUTV_OFF + (size_t)bid*1024 + d*8 + qb + j] = acc[j];
}

// ---------------- finalize: 32 blocks, coalesced chunk reduce ----------------
__global__ __launch_bounds__(256) void finalize_kernel(const float* __restrict__ ws,
    float* __restrict__ out){
  __shared__ float dsum[8];
  __shared__ float red[8][32];
  const int t = threadIdx.x, bid = blockIdx.x;

  if (t < 64){
    const int q = t >> 3, i = t & 7;
    float s = 0.f;
    for (int j = 0; j < 32; j++) s += ws[DENOM_OFF + q*NCH_ + i + 8*j];
#pragma unroll
    for (int off = 4; off > 0; off >>= 1) s += __shfl_xor(s, off, 64);
    if (i == 0) dsum[q] = s;
  }

  const int ol = t & 31, part = t >> 5;
  float s = 0.f;
  for (int j = 0; j < 32; j++)
    s += ws[OUTV_OFF + (size_t)(part + 8*j)*1024 + bid*32 + ol];
  red[part][ol] = s;
  __syncthreads();

  if (t < 32){
    float a = 0.f;
#pragma unroll
    for (int p = 0; p < 8; p++) a += red[p][t];
    const int o = bid*32 + t;
    out[o] = a / dsum[o & 7];
  }
}

extern "C" void kernel_launch(void* const* d_in, const int* in_sizes, int n_in,
                              void* d_out, int out_size, void* d_ws, size_t ws_size,
                              hipStream_t stream){
  const float* query=(const float*)d_in[0];
  const float* keys =(const float*)d_in[1];
  const float* value=(const float*)d_in[2];
  const float* dist =(const float*)d_in[3];
  const int*   mask =(const int*)d_in[4];
  const float* W1   =(const float*)d_in[5];
  const float* b1   =(const float*)d_in[6];
  const float* W2   =(const float*)d_in[7];
  const float* b2   =(const float*)d_in[8];
  float* out=(float*)d_out;
  float* scores=out+1024;
  float* ws=(float*)d_ws;

  prep_kernel      <<<17,256,0,stream>>>(query,W1,b1,ws);
  scores_kernel    <<<1024,256,0,stream>>>(keys,dist,W2,b2,ws,scores);
  softmax_pv_kernel<<<NCH_,256,0,stream>>>(value,mask,scores,ws);
  finalize_kernel  <<<32,256,0,stream>>>(ws,out);
}